// Round 1
// baseline (857.173 us; speedup 1.0000x reference)
//
#include <hip/hip_runtime.h>

typedef _Float16 half8 __attribute__((ext_vector_type(8)));
typedef _Float16 half4v __attribute__((ext_vector_type(4)));
typedef float f32x4 __attribute__((ext_vector_type(4)));

#define MFMA16(a, b, c) __builtin_amdgcn_mfma_f32_16x16x32_f16((a), (b), (c), 0, 0, 0)

__device__ __forceinline__ void gl2lds16(const void* g, void* l) {
  __builtin_amdgcn_global_load_lds(
      (const __attribute__((address_space(1))) void*)g,
      (__attribute__((address_space(3))) void*)l, 16, 0, 0);
}

// ---------------- cast f32 -> f16 (n multiple of 2048) ----------------
__global__ void cast_f16_kernel(const float* __restrict__ in, _Float16* __restrict__ out, int n) {
  int i = (blockIdx.x * 256 + threadIdx.x) * 8;
  if (i >= n) return;
  float4 a = *(const float4*)(in + i);
  float4 b = *(const float4*)(in + i + 4);
  half8 o;
  o[0] = (_Float16)a.x; o[1] = (_Float16)a.y; o[2] = (_Float16)a.z; o[3] = (_Float16)a.w;
  o[4] = (_Float16)b.x; o[5] = (_Float16)b.y; o[6] = (_Float16)b.z; o[7] = (_Float16)b.w;
  *(half8*)(out + i) = o;
}

// ---------------- LayerNorm + AdaLN modulate -> fp16 ----------------
// out = LN(x) * (scale+1) + shift, scale = ada[sidx]+cond[b,sidx], shift = ada[hidx]+cond[b,hidx]
__global__ void ln_mod_kernel(const float* __restrict__ x, const float* __restrict__ cond,
                              const float* __restrict__ ada, _Float16* __restrict__ out,
                              int sidx, int hidx) {
  int row = blockIdx.x;        // 0..4095 (b*1024 + l)
  int b = row >> 10;
  int t = threadIdx.x;         // 256
  const float* xr = x + (size_t)row * 1024;
  float4 v = *(const float4*)(xr + t * 4);
  float s = v.x + v.y + v.z + v.w;
  float s2 = v.x * v.x + v.y * v.y + v.z * v.z + v.w * v.w;
#pragma unroll
  for (int m = 32; m >= 1; m >>= 1) {
    s += __shfl_xor(s, m, 64);
    s2 += __shfl_xor(s2, m, 64);
  }
  __shared__ float red[8];
  int w = t >> 6;
  if ((t & 63) == 0) { red[w * 2] = s; red[w * 2 + 1] = s2; }
  __syncthreads();
  s = red[0] + red[2] + red[4] + red[6];
  s2 = red[1] + red[3] + red[5] + red[7];
  float mu = s * (1.f / 1024.f);
  float var = s2 * (1.f / 1024.f) - mu * mu;
  float rstd = rsqrtf(var + 1e-5f);
  int c = t * 4;
  float4 sc = *(const float4*)(cond + (size_t)b * 6144 + sidx * 1024 + c);
  float4 sh = *(const float4*)(cond + (size_t)b * 6144 + hidx * 1024 + c);
  float4 sa = *(const float4*)(ada + sidx * 1024 + c);
  float4 ha = *(const float4*)(ada + hidx * 1024 + c);
  half4v o;
  o[0] = (_Float16)((v.x - mu) * rstd * (sc.x + sa.x + 1.f) + sh.x + ha.x);
  o[1] = (_Float16)((v.y - mu) * rstd * (sc.y + sa.y + 1.f) + sh.y + ha.y);
  o[2] = (_Float16)((v.z - mu) * rstd * (sc.z + sa.z + 1.f) + sh.z + ha.z);
  o[3] = (_Float16)((v.w - mu) * rstd * (sc.w + sa.w + 1.f) + sh.w + ha.w);
  *(half4v*)(out + (size_t)row * 1024 + c) = o;
}

// ---------------- GEMM: C = A[M,K] * W[N,K]^T, fp16 in, fp32 acc ----------------
// EPI 0: store fp16 to [b*16+h][l][64] layout (QKV)
// EPI 1: out fp32 = res + (acc + bias)*gamma  (proj / ffn2, N must be 1024)
// EPI 2: out fp16 = gelu(acc + bias)          (ffn1, N must be 4096)
template <int EPI>
__global__ __launch_bounds__(256) void gemm_f16(
    const _Float16* __restrict__ A, const _Float16* __restrict__ W,
    int M, int N, int K, void* __restrict__ outp,
    const float* __restrict__ bias, const float* __restrict__ res,
    const float* __restrict__ cond, const float* __restrict__ ada, int gidx) {
  __shared__ __align__(16) _Float16 lA[128 * 32];
  __shared__ __align__(16) _Float16 lB[128 * 32];
  int t = threadIdx.x;
  int lane = t & 63;
  int w = t >> 6;
  int wr = w >> 1, wc = w & 1;
  int l16 = lane & 15, lg = lane >> 4;
  int bm = blockIdx.y * 128, bn = blockIdx.x * 128;
  f32x4 acc[4][4] = {};
  int e0 = t * 8;
  int e1 = 2048 + t * 8;
  int r0 = e0 >> 5, c0 = e0 & 31;
  int r1 = e1 >> 5, c1 = e1 & 31;
  const _Float16* Ab = A + (size_t)bm * K;
  const _Float16* Wb = W + (size_t)bn * K;
  for (int kt = 0; kt < K; kt += 32) {
    gl2lds16(Ab + (size_t)r0 * K + kt + c0, &lA[e0]);
    gl2lds16(Ab + (size_t)r1 * K + kt + c1, &lA[e1]);
    gl2lds16(Wb + (size_t)r0 * K + kt + c0, &lB[e0]);
    gl2lds16(Wb + (size_t)r1 * K + kt + c1, &lB[e1]);
    __syncthreads();
    half8 af[4], bf[4];
#pragma unroll
    for (int m = 0; m < 4; ++m)
      af[m] = *(const half8*)&lA[(wr * 64 + m * 16 + l16) * 32 + lg * 8];
#pragma unroll
    for (int n = 0; n < 4; ++n)
      bf[n] = *(const half8*)&lB[(wc * 64 + n * 16 + l16) * 32 + lg * 8];
#pragma unroll
    for (int m = 0; m < 4; ++m)
#pragma unroll
      for (int n = 0; n < 4; ++n)
        acc[m][n] = MFMA16(af[m], bf[n], acc[m][n]);
    __syncthreads();
  }
#pragma unroll
  for (int m = 0; m < 4; ++m) {
#pragma unroll
    for (int n = 0; n < 4; ++n) {
      int gc = bn + wc * 64 + n * 16 + l16;
      int gr0 = bm + wr * 64 + m * 16 + lg * 4;
#pragma unroll
      for (int r = 0; r < 4; ++r) {
        int gr = gr0 + r;
        float v = acc[m][n][r];
        if constexpr (EPI == 0) {
          int b = gr >> 10, l = gr & 1023, h = gc >> 6, hd = gc & 63;
          ((_Float16*)outp)[(((size_t)(b * 16 + h)) * 1024 + l) * 64 + hd] = (_Float16)v;
        } else if constexpr (EPI == 1) {
          float g = ada[gidx * 1024 + gc] + cond[(size_t)(gr >> 10) * 6144 + gidx * 1024 + gc];
          ((float*)outp)[(size_t)gr * 1024 + gc] =
              res[(size_t)gr * 1024 + gc] + (v + bias[gc]) * g;
        } else {
          float xx = v + bias[gc];
          float u = 0.7978845608028654f * (xx + 0.044715f * xx * xx * xx);
          float e = __expf(2.f * u);
          float th = (e - 1.f) / (e + 1.f);
          ((_Float16*)outp)[(size_t)gr * 4096 + gc] = (_Float16)(0.5f * xx * (1.f + th));
        }
      }
    }
  }
}

// ---------------- transpose V: [bh][key][64] -> [bh][64][key] ----------------
__global__ void transpose_v_kernel(const _Float16* __restrict__ v16, _Float16* __restrict__ vt16) {
  int bh = blockIdx.y, ktile = blockIdx.x;
  __shared__ _Float16 tile[64][72];
  int t = threadIdx.x;
  int r = t >> 2, c0 = (t & 3) * 16;
  const _Float16* src = v16 + ((size_t)bh * 1024 + ktile * 64) * 64;
  half8 a = *(const half8*)(src + r * 64 + c0);
  half8 b = *(const half8*)(src + r * 64 + c0 + 8);
#pragma unroll
  for (int j = 0; j < 8; ++j) {
    tile[r][c0 + j] = a[j];
    tile[r][c0 + 8 + j] = b[j];
  }
  __syncthreads();
  half8 oa, ob;
#pragma unroll
  for (int j = 0; j < 8; ++j) {
    oa[j] = tile[c0 + j][r];
    ob[j] = tile[c0 + 8 + j][r];
  }
  _Float16* dst = vt16 + ((size_t)bh * 64 + r) * 1024 + ktile * 64 + c0;
  *(half8*)dst = oa;
  *(half8*)(dst + 8) = ob;
}

// ---------------- fused flash attention ----------------
// grid (L/64, B*H), 256 thr = 4 waves, wave owns 16 q rows. KV tile = 64.
__global__ __launch_bounds__(256) void attn_kernel(
    const _Float16* __restrict__ q16, const _Float16* __restrict__ k16,
    const _Float16* __restrict__ vt16, const float* __restrict__ bias,
    _Float16* __restrict__ o16) {
  int bh = blockIdx.y;
  int qb = blockIdx.x;
  int t = threadIdx.x, w = t >> 6, lane = t & 63;
  int l16 = lane & 15, lg = lane >> 4;
  int qRowW = qb * 64 + w * 16;
  const size_t bhoff = (size_t)bh * 1024 * 64;
  half8 aq[2];
#pragma unroll
  for (int ks = 0; ks < 2; ++ks)
    aq[ks] = *(const half8*)(q16 + bhoff + (size_t)(qRowW + l16) * 64 + ks * 32 + lg * 8);
  f32x4 oacc[4] = {};
  float mrun[4], lrun[4];
#pragma unroll
  for (int r = 0; r < 4; ++r) { mrun[r] = -1e30f; lrun[r] = 0.f; }
  __shared__ __align__(16) _Float16 pbuf[4][16 * 64];
  const float* bb = bias + (size_t)bh * 1024 * 1024;
  const _Float16* vb = vt16 + (size_t)bh * 64 * 1024;
  for (int kt = 0; kt < 1024; kt += 64) {
    f32x4 s[4] = {};
#pragma unroll
    for (int ks = 0; ks < 2; ++ks) {
#pragma unroll
      for (int n = 0; n < 4; ++n) {
        half8 bk = *(const half8*)(k16 + bhoff + (size_t)(kt + n * 16 + l16) * 64 + ks * 32 + lg * 8);
        s[n] = MFMA16(aq[ks], bk, s[n]);
      }
    }
    float p[4][4];
#pragma unroll
    for (int r = 0; r < 4; ++r) {
      const float* bp = bb + (size_t)(qRowW + lg * 4 + r) * 1024 + kt + l16;
#pragma unroll
      for (int n = 0; n < 4; ++n)
        p[n][r] = s[n][r] * 0.03125f + bp[n * 16];
    }
#pragma unroll
    for (int r = 0; r < 4; ++r) {
      float tm = fmaxf(fmaxf(p[0][r], p[1][r]), fmaxf(p[2][r], p[3][r]));
#pragma unroll
      for (int msk = 1; msk < 16; msk <<= 1) tm = fmaxf(tm, __shfl_xor(tm, msk, 64));
      float mnew = fmaxf(mrun[r], tm);
      float scl = __expf(mrun[r] - mnew);
      mrun[r] = mnew;
      float ts = 0.f;
#pragma unroll
      for (int n = 0; n < 4; ++n) {
        p[n][r] = __expf(p[n][r] - mnew);
        ts += p[n][r];
      }
#pragma unroll
      for (int msk = 1; msk < 16; msk <<= 1) ts += __shfl_xor(ts, msk, 64);
      lrun[r] = lrun[r] * scl + ts;
#pragma unroll
      for (int n = 0; n < 4; ++n) {
        oacc[n][r] *= scl;
        pbuf[w][(lg * 4 + r) * 64 + n * 16 + l16] = (_Float16)p[n][r];
      }
    }
#pragma unroll
    for (int ks = 0; ks < 2; ++ks) {
      half8 ap = *(const half8*)&pbuf[w][l16 * 64 + ks * 32 + lg * 8];
#pragma unroll
      for (int n = 0; n < 4; ++n) {
        half8 bv = *(const half8*)(vb + (size_t)(n * 16 + l16) * 1024 + kt + ks * 32 + lg * 8);
        oacc[n] = MFMA16(ap, bv, oacc[n]);
      }
    }
  }
  int b = bh >> 4, h = bh & 15;
#pragma unroll
  for (int r = 0; r < 4; ++r) {
    float inv = 1.f / lrun[r];
    int row = qRowW + lg * 4 + r;
#pragma unroll
    for (int n = 0; n < 4; ++n)
      o16[((size_t)b * 1024 + row) * 1024 + h * 64 + n * 16 + l16] =
          (_Float16)(oacc[n][r] * inv);
  }
}

extern "C" void kernel_launch(void* const* d_in, const int* in_sizes, int n_in,
                              void* d_out, int out_size, void* d_ws, size_t ws_size,
                              hipStream_t stream) {
  const float* x = (const float*)d_in[0];
  const float* ctx = (const float*)d_in[1];
  const float* cond = (const float*)d_in[2];
  const float* bias = (const float*)d_in[3];
  const float* ada = (const float*)d_in[4];
  const float* Wq = (const float*)d_in[5];
  const float* Wk = (const float*)d_in[6];
  const float* Wv = (const float*)d_in[7];
  const float* Wo = (const float*)d_in[8];
  const float* bo = (const float*)d_in[9];
  const float* W1 = (const float*)d_in[10];
  const float* b1 = (const float*)d_in[11];
  const float* W2 = (const float*)d_in[12];
  const float* b2 = (const float*)d_in[13];

  char* ws = (char*)d_ws;
  const size_t MB = 1u << 20;
  _Float16* wq16 = (_Float16*)(ws + 0 * MB);
  _Float16* wk16 = (_Float16*)(ws + 2 * MB);
  _Float16* wv16 = (_Float16*)(ws + 4 * MB);
  _Float16* wo16 = (_Float16*)(ws + 6 * MB);
  _Float16* w116 = (_Float16*)(ws + 8 * MB);
  _Float16* w216 = (_Float16*)(ws + 16 * MB);
  _Float16* modx = (_Float16*)(ws + 24 * MB);  // reused for mod_f
  _Float16* ctx16 = (_Float16*)(ws + 32 * MB);
  _Float16* q16 = (_Float16*)(ws + 40 * MB);
  _Float16* k16 = (_Float16*)(ws + 48 * MB);
  _Float16* v16 = (_Float16*)(ws + 56 * MB);
  _Float16* vt16 = (_Float16*)(ws + 64 * MB);
  _Float16* h16 = (_Float16*)(ws + 40 * MB);  // reuses q/k/v/vt region (dead by then)
  _Float16* o16 = (_Float16*)(ws + 72 * MB);
  float* x1 = (float*)(ws + 80 * MB);

  cast_f16_kernel<<<2048, 256, 0, stream>>>(ctx, ctx16, 4 * 1024 * 1024);
  cast_f16_kernel<<<512, 256, 0, stream>>>(Wq, wq16, 1024 * 1024);
  cast_f16_kernel<<<512, 256, 0, stream>>>(Wk, wk16, 1024 * 1024);
  cast_f16_kernel<<<512, 256, 0, stream>>>(Wv, wv16, 1024 * 1024);
  cast_f16_kernel<<<512, 256, 0, stream>>>(Wo, wo16, 1024 * 1024);
  cast_f16_kernel<<<2048, 256, 0, stream>>>(W1, w116, 4 * 1024 * 1024);
  cast_f16_kernel<<<2048, 256, 0, stream>>>(W2, w216, 4 * 1024 * 1024);

  ln_mod_kernel<<<4096, 256, 0, stream>>>(x, cond, ada, modx, 2, 4);

  dim3 gN1024(8, 32);
  gemm_f16<0><<<gN1024, 256, 0, stream>>>(modx, wq16, 4096, 1024, 1024, q16,
                                          nullptr, nullptr, nullptr, nullptr, 0);
  gemm_f16<0><<<gN1024, 256, 0, stream>>>(ctx16, wk16, 4096, 1024, 1024, k16,
                                          nullptr, nullptr, nullptr, nullptr, 0);
  gemm_f16<0><<<gN1024, 256, 0, stream>>>(ctx16, wv16, 4096, 1024, 1024, v16,
                                          nullptr, nullptr, nullptr, nullptr, 0);

  transpose_v_kernel<<<dim3(16, 64), 256, 0, stream>>>(v16, vt16);

  attn_kernel<<<dim3(16, 64), 256, 0, stream>>>(q16, k16, vt16, bias, o16);

  gemm_f16<1><<<gN1024, 256, 0, stream>>>(o16, wo16, 4096, 1024, 1024, x1,
                                          bo, x, cond, ada, 0);

  ln_mod_kernel<<<4096, 256, 0, stream>>>(x1, cond, ada, modx, 3, 5);

  gemm_f16<2><<<dim3(32, 32), 256, 0, stream>>>(modx, w116, 4096, 4096, 1024, h16,
                                                b1, nullptr, nullptr, nullptr, 0);

  gemm_f16<1><<<gN1024, 256, 0, stream>>>(h16, w216, 4096, 1024, 4096, d_out,
                                          b2, x1, cond, ada, 1);
}

// Round 2
// 849.464 us; speedup vs baseline: 1.0091x; 1.0091x over previous
//
#include <hip/hip_runtime.h>

typedef _Float16 half8 __attribute__((ext_vector_type(8)));
typedef _Float16 half4v __attribute__((ext_vector_type(4)));
typedef float f32x4 __attribute__((ext_vector_type(4)));

#define MFMA16(a, b, c) __builtin_amdgcn_mfma_f32_16x16x32_f16((a), (b), (c), 0, 0, 0)

__device__ __forceinline__ void gl2lds16(const void* g, void* l) {
  __builtin_amdgcn_global_load_lds(
      (const __attribute__((address_space(1))) void*)g,
      (__attribute__((address_space(3))) void*)l, 16, 0, 0);
}

// ---------------- fused cast f32 -> f16 for all 7 tensors ----------------
__device__ __forceinline__ void cast8(const float* s, _Float16* d, int i) {
  float4 a = *(const float4*)(s + i);
  float4 b = *(const float4*)(s + i + 4);
  half8 o;
  o[0] = (_Float16)a.x; o[1] = (_Float16)a.y; o[2] = (_Float16)a.z; o[3] = (_Float16)a.w;
  o[4] = (_Float16)b.x; o[5] = (_Float16)b.y; o[6] = (_Float16)b.z; o[7] = (_Float16)b.w;
  *(half8*)(d + i) = o;
}

__global__ void cast_all_kernel(const float* s0, const float* s1, const float* s2,
                                const float* s3, const float* s4, const float* s5,
                                const float* s6, _Float16* d0, _Float16* d1,
                                _Float16* d2, _Float16* d3, _Float16* d4,
                                _Float16* d5, _Float16* d6) {
  int b = blockIdx.x;
  const float* s;
  _Float16* d;
  int off;
  if (b < 2048)      { s = s0; d = d0; off = b; }
  else if (b < 2560) { s = s1; d = d1; off = b - 2048; }
  else if (b < 3072) { s = s2; d = d2; off = b - 2560; }
  else if (b < 3584) { s = s3; d = d3; off = b - 3072; }
  else if (b < 4096) { s = s4; d = d4; off = b - 3584; }
  else if (b < 6144) { s = s5; d = d5; off = b - 4096; }
  else               { s = s6; d = d6; off = b - 6144; }
  cast8(s, d, (off * 256 + threadIdx.x) * 8);
}

// ---------------- LayerNorm + AdaLN modulate -> fp16 ----------------
__global__ void ln_mod_kernel(const float* __restrict__ x, const float* __restrict__ cond,
                              const float* __restrict__ ada, _Float16* __restrict__ out,
                              int sidx, int hidx) {
  int row = blockIdx.x;        // 0..4095 (b*1024 + l)
  int b = row >> 10;
  int t = threadIdx.x;         // 256
  const float* xr = x + (size_t)row * 1024;
  float4 v = *(const float4*)(xr + t * 4);
  float s = v.x + v.y + v.z + v.w;
  float s2 = v.x * v.x + v.y * v.y + v.z * v.z + v.w * v.w;
#pragma unroll
  for (int m = 32; m >= 1; m >>= 1) {
    s += __shfl_xor(s, m, 64);
    s2 += __shfl_xor(s2, m, 64);
  }
  __shared__ float red[8];
  int w = t >> 6;
  if ((t & 63) == 0) { red[w * 2] = s; red[w * 2 + 1] = s2; }
  __syncthreads();
  s = red[0] + red[2] + red[4] + red[6];
  s2 = red[1] + red[3] + red[5] + red[7];
  float mu = s * (1.f / 1024.f);
  float var = s2 * (1.f / 1024.f) - mu * mu;
  float rstd = rsqrtf(var + 1e-5f);
  int c = t * 4;
  float4 sc = *(const float4*)(cond + (size_t)b * 6144 + sidx * 1024 + c);
  float4 sh = *(const float4*)(cond + (size_t)b * 6144 + hidx * 1024 + c);
  float4 sa = *(const float4*)(ada + sidx * 1024 + c);
  float4 ha = *(const float4*)(ada + hidx * 1024 + c);
  half4v o;
  o[0] = (_Float16)((v.x - mu) * rstd * (sc.x + sa.x + 1.f) + sh.x + ha.x);
  o[1] = (_Float16)((v.y - mu) * rstd * (sc.y + sa.y + 1.f) + sh.y + ha.y);
  o[2] = (_Float16)((v.z - mu) * rstd * (sc.z + sa.z + 1.f) + sh.z + ha.z);
  o[3] = (_Float16)((v.w - mu) * rstd * (sc.w + sa.w + 1.f) + sh.w + ha.w);
  *(half4v*)(out + (size_t)row * 1024 + c) = o;
}

// ---------------- GEMM: C = A[M,K] * W[N,K]^T, fp16 in, fp32 acc ----------------
template <int EPI>
__global__ __launch_bounds__(256) void gemm_f16(
    const _Float16* __restrict__ A, const _Float16* __restrict__ W,
    int M, int N, int K, void* __restrict__ outp,
    const float* __restrict__ bias, const float* __restrict__ res,
    const float* __restrict__ cond, const float* __restrict__ ada, int gidx) {
  __shared__ __align__(16) _Float16 lA[128 * 32];
  __shared__ __align__(16) _Float16 lB[128 * 32];
  int t = threadIdx.x;
  int lane = t & 63;
  int w = t >> 6;
  int wr = w >> 1, wc = w & 1;
  int l16 = lane & 15, lg = lane >> 4;
  int bm = blockIdx.y * 128, bn = blockIdx.x * 128;
  f32x4 acc[4][4] = {};
  int e0 = t * 8;
  int e1 = 2048 + t * 8;
  int r0 = e0 >> 5, c0 = e0 & 31;
  int r1 = e1 >> 5, c1 = e1 & 31;
  const _Float16* Ab = A + (size_t)bm * K;
  const _Float16* Wb = W + (size_t)bn * K;
  for (int kt = 0; kt < K; kt += 32) {
    gl2lds16(Ab + (size_t)r0 * K + kt + c0, &lA[e0]);
    gl2lds16(Ab + (size_t)r1 * K + kt + c1, &lA[e1]);
    gl2lds16(Wb + (size_t)r0 * K + kt + c0, &lB[e0]);
    gl2lds16(Wb + (size_t)r1 * K + kt + c1, &lB[e1]);
    __syncthreads();
    half8 af[4], bf[4];
#pragma unroll
    for (int m = 0; m < 4; ++m)
      af[m] = *(const half8*)&lA[(wr * 64 + m * 16 + l16) * 32 + lg * 8];
#pragma unroll
    for (int n = 0; n < 4; ++n)
      bf[n] = *(const half8*)&lB[(wc * 64 + n * 16 + l16) * 32 + lg * 8];
#pragma unroll
    for (int m = 0; m < 4; ++m)
#pragma unroll
      for (int n = 0; n < 4; ++n)
        acc[m][n] = MFMA16(af[m], bf[n], acc[m][n]);
    __syncthreads();
  }
#pragma unroll
  for (int m = 0; m < 4; ++m) {
#pragma unroll
    for (int n = 0; n < 4; ++n) {
      int gc = bn + wc * 64 + n * 16 + l16;
      int gr0 = bm + wr * 64 + m * 16 + lg * 4;
#pragma unroll
      for (int r = 0; r < 4; ++r) {
        int gr = gr0 + r;
        float v = acc[m][n][r];
        if constexpr (EPI == 0) {
          int b = gr >> 10, l = gr & 1023, h = gc >> 6, hd = gc & 63;
          ((_Float16*)outp)[(((size_t)(b * 16 + h)) * 1024 + l) * 64 + hd] = (_Float16)v;
        } else if constexpr (EPI == 1) {
          float g = ada[gidx * 1024 + gc] + cond[(size_t)(gr >> 10) * 6144 + gidx * 1024 + gc];
          ((float*)outp)[(size_t)gr * 1024 + gc] =
              res[(size_t)gr * 1024 + gc] + (v + bias[gc]) * g;
        } else {
          float xx = v + bias[gc];
          float u = 0.7978845608028654f * (xx + 0.044715f * xx * xx * xx);
          float e = __expf(2.f * u);
          float th = (e - 1.f) / (e + 1.f);
          ((_Float16*)outp)[(size_t)gr * 4096 + gc] = (_Float16)(0.5f * xx * (1.f + th));
        }
      }
    }
  }
}

// ---------------- transpose V: [bh][key][64] -> [bh][64][key] ----------------
__global__ void transpose_v_kernel(const _Float16* __restrict__ v16, _Float16* __restrict__ vt16) {
  int bh = blockIdx.y, ktile = blockIdx.x;
  __shared__ _Float16 tile[64][72];
  int t = threadIdx.x;
  int r = t >> 2, c0 = (t & 3) * 16;
  const _Float16* src = v16 + ((size_t)bh * 1024 + ktile * 64) * 64;
  half8 a = *(const half8*)(src + r * 64 + c0);
  half8 b = *(const half8*)(src + r * 64 + c0 + 8);
#pragma unroll
  for (int j = 0; j < 8; ++j) {
    tile[r][c0 + j] = a[j];
    tile[r][c0 + 8 + j] = b[j];
  }
  __syncthreads();
  half8 oa, ob;
#pragma unroll
  for (int j = 0; j < 8; ++j) {
    oa[j] = tile[c0 + j][r];
    ob[j] = tile[c0 + 8 + j][r];
  }
  _Float16* dst = vt16 + ((size_t)bh * 64 + r) * 1024 + ktile * 64 + c0;
  *(half8*)dst = oa;
  *(half8*)(dst + 8) = ob;
}

// ---------------- fused flash attention v2 (swapped QK^T) ----------------
// grid (L/64, B*H), 256 thr = 4 waves, wave owns 16 q rows. KV tile = 64.
// S^T = mfma(K,Q): lane holds keys kt+kk*16+lg*4+r for query l16 -> bias is
// float4/lane, softmax reduce = in-lane + 2 shfl. P redistributed via padded LDS.
__global__ __launch_bounds__(256, 4) void attn_kernel(
    const _Float16* __restrict__ q16, const _Float16* __restrict__ k16,
    const _Float16* __restrict__ vt16, const float* __restrict__ bias,
    _Float16* __restrict__ o16) {
  int bh = blockIdx.y;
  int qb = blockIdx.x;
  int t = threadIdx.x, w = t >> 6, lane = t & 63;
  int l16 = lane & 15, lg = lane >> 4;
  int qRowW = qb * 64 + w * 16;
  const size_t bhoff = (size_t)bh * 65536;
  half8 aq[2];
#pragma unroll
  for (int ks = 0; ks < 2; ++ks)
    aq[ks] = *(const half8*)(q16 + bhoff + (size_t)(qRowW + l16) * 64 + ks * 32 + lg * 8);
  f32x4 oacc[4] = {};
  float mrun = -1e30f, lrun = 0.f;  // per-lane: stats for query l16 (replicated over lg)
  __shared__ __align__(16) _Float16 pbuf[4][16][80];  // 160B row stride: b128-conflict-free
  const float* bb = bias + (size_t)bh * 1048576 + (size_t)(qRowW + l16) * 1024;
  const _Float16* kb = k16 + bhoff;
  const _Float16* vb = vt16 + bhoff;
  // prefetch bias tile 0
  f32x4 nb[4];
#pragma unroll
  for (int kk = 0; kk < 4; ++kk) nb[kk] = *(const f32x4*)(bb + kk * 16 + lg * 4);
  for (int kt = 0; kt < 1024; kt += 64) {
    // QK^T swapped: s[kk] row = key (lg*4+r), col = query (l16)
    f32x4 s[4] = {};
#pragma unroll
    for (int ks = 0; ks < 2; ++ks) {
#pragma unroll
      for (int kk = 0; kk < 4; ++kk) {
        half8 kf = *(const half8*)(kb + (size_t)(kt + kk * 16 + l16) * 64 + ks * 32 + lg * 8);
        s[kk] = MFMA16(kf, aq[ks], s[kk]);
      }
    }
    float p[4][4];
    float tm = -1e30f;
#pragma unroll
    for (int kk = 0; kk < 4; ++kk)
#pragma unroll
      for (int r = 0; r < 4; ++r) {
        p[kk][r] = s[kk][r] * 0.03125f + nb[kk][r];
        tm = fmaxf(tm, p[kk][r]);
      }
    // prefetch bias for next tile (overlaps softmax + PV)
    if (kt < 960) {
#pragma unroll
      for (int kk = 0; kk < 4; ++kk)
        nb[kk] = *(const f32x4*)(bb + kt + 64 + kk * 16 + lg * 4);
    }
    tm = fmaxf(tm, __shfl_xor(tm, 16, 64));
    tm = fmaxf(tm, __shfl_xor(tm, 32, 64));
    int noskip = !__all(tm <= mrun);  // exact defer-max: skip only when old max still valid
    float mnew = noskip ? fmaxf(mrun, tm) : mrun;
    float ts = 0.f;
#pragma unroll
    for (int kk = 0; kk < 4; ++kk)
#pragma unroll
      for (int r = 0; r < 4; ++r) {
        p[kk][r] = exp2f((p[kk][r] - mnew) * 1.442695041f);
        ts += p[kk][r];
      }
    ts += __shfl_xor(ts, 16, 64);
    ts += __shfl_xor(ts, 32, 64);
    if (noskip) {
      float scl = exp2f((mrun - mnew) * 1.442695041f);
      lrun = lrun * scl + ts;
      mrun = mnew;
      float sclr[4];
#pragma unroll
      for (int r = 0; r < 4; ++r) sclr[r] = __shfl(scl, lg * 4 + r, 16);
#pragma unroll
      for (int n = 0; n < 4; ++n)
#pragma unroll
        for (int r = 0; r < 4; ++r) oacc[n][r] *= sclr[r];
    } else {
      lrun += ts;
    }
    // store P: row = query l16, col = key-in-tile kk*16+lg*4+r
#pragma unroll
    for (int kk = 0; kk < 4; ++kk) {
      half4v ph;
#pragma unroll
      for (int r = 0; r < 4; ++r) ph[r] = (_Float16)p[kk][r];
      *(half4v*)&pbuf[w][l16][kk * 16 + lg * 4] = ph;
    }
    // PV: A = P (query rows), B = V^T (hd rows)
#pragma unroll
    for (int ks = 0; ks < 2; ++ks) {
      half8 ap = *(const half8*)&pbuf[w][l16][ks * 32 + lg * 8];
#pragma unroll
      for (int n = 0; n < 4; ++n) {
        half8 bv = *(const half8*)(vb + (size_t)(n * 16 + l16) * 1024 + kt + ks * 32 + lg * 8);
        oacc[n] = MFMA16(ap, bv, oacc[n]);
      }
    }
  }
  float inv = 1.f / lrun;
  float invr[4];
#pragma unroll
  for (int r = 0; r < 4; ++r) invr[r] = __shfl(inv, lg * 4 + r, 16);
  int b = bh >> 4, h = bh & 15;
#pragma unroll
  for (int r = 0; r < 4; ++r) {
    int row = qRowW + lg * 4 + r;
#pragma unroll
    for (int n = 0; n < 4; ++n)
      o16[((size_t)b * 1024 + row) * 1024 + h * 64 + n * 16 + l16] =
          (_Float16)(oacc[n][r] * invr[r]);
  }
}

extern "C" void kernel_launch(void* const* d_in, const int* in_sizes, int n_in,
                              void* d_out, int out_size, void* d_ws, size_t ws_size,
                              hipStream_t stream) {
  const float* x = (const float*)d_in[0];
  const float* ctx = (const float*)d_in[1];
  const float* cond = (const float*)d_in[2];
  const float* bias = (const float*)d_in[3];
  const float* ada = (const float*)d_in[4];
  const float* Wq = (const float*)d_in[5];
  const float* Wk = (const float*)d_in[6];
  const float* Wv = (const float*)d_in[7];
  const float* Wo = (const float*)d_in[8];
  const float* bo = (const float*)d_in[9];
  const float* W1 = (const float*)d_in[10];
  const float* b1 = (const float*)d_in[11];
  const float* W2 = (const float*)d_in[12];
  const float* b2 = (const float*)d_in[13];

  char* ws = (char*)d_ws;
  const size_t MB = 1u << 20;
  _Float16* wq16 = (_Float16*)(ws + 0 * MB);
  _Float16* wk16 = (_Float16*)(ws + 2 * MB);
  _Float16* wv16 = (_Float16*)(ws + 4 * MB);
  _Float16* wo16 = (_Float16*)(ws + 6 * MB);
  _Float16* w116 = (_Float16*)(ws + 8 * MB);
  _Float16* w216 = (_Float16*)(ws + 16 * MB);
  _Float16* modx = (_Float16*)(ws + 24 * MB);  // reused for mod_f
  _Float16* ctx16 = (_Float16*)(ws + 32 * MB);
  _Float16* q16 = (_Float16*)(ws + 40 * MB);
  _Float16* k16 = (_Float16*)(ws + 48 * MB);
  _Float16* v16 = (_Float16*)(ws + 56 * MB);
  _Float16* vt16 = (_Float16*)(ws + 64 * MB);
  _Float16* h16 = (_Float16*)(ws + 40 * MB);  // reuses q/k/v/vt region (dead by then)
  _Float16* o16 = (_Float16*)(ws + 72 * MB);
  float* x1 = (float*)(ws + 80 * MB);

  cast_all_kernel<<<8192, 256, 0, stream>>>(ctx, Wq, Wk, Wv, Wo, W1, W2,
                                            ctx16, wq16, wk16, wv16, wo16, w116, w216);

  ln_mod_kernel<<<4096, 256, 0, stream>>>(x, cond, ada, modx, 2, 4);

  dim3 gN1024(8, 32);
  gemm_f16<0><<<gN1024, 256, 0, stream>>>(modx, wq16, 4096, 1024, 1024, q16,
                                          nullptr, nullptr, nullptr, nullptr, 0);
  gemm_f16<0><<<gN1024, 256, 0, stream>>>(ctx16, wk16, 4096, 1024, 1024, k16,
                                          nullptr, nullptr, nullptr, nullptr, 0);
  gemm_f16<0><<<gN1024, 256, 0, stream>>>(ctx16, wv16, 4096, 1024, 1024, v16,
                                          nullptr, nullptr, nullptr, nullptr, 0);

  transpose_v_kernel<<<dim3(16, 64), 256, 0, stream>>>(v16, vt16);

  attn_kernel<<<dim3(16, 64), 256, 0, stream>>>(q16, k16, vt16, bias, o16);

  gemm_f16<1><<<gN1024, 256, 0, stream>>>(o16, wo16, 4096, 1024, 1024, x1,
                                          bo, x, cond, ada, 0);

  ln_mod_kernel<<<4096, 256, 0, stream>>>(x1, cond, ada, modx, 3, 5);

  gemm_f16<2><<<dim3(32, 32), 256, 0, stream>>>(modx, w116, 4096, 4096, 1024, h16,
                                                b1, nullptr, nullptr, nullptr, 0);

  gemm_f16<1><<<gN1024, 256, 0, stream>>>(h16, w216, 4096, 1024, 4096, d_out,
                                          b2, x1, cond, ada, 1);
}

// Round 4
// 797.748 us; speedup vs baseline: 1.0745x; 1.0648x over previous
//
#include <hip/hip_runtime.h>

typedef _Float16 half8 __attribute__((ext_vector_type(8)));
typedef _Float16 half4v __attribute__((ext_vector_type(4)));
typedef float f32x4 __attribute__((ext_vector_type(4)));

#define MFMA16(a, b, c) __builtin_amdgcn_mfma_f32_16x16x32_f16((a), (b), (c), 0, 0, 0)

__device__ __forceinline__ void gl2lds16(const void* g, void* l) {
  __builtin_amdgcn_global_load_lds(
      (const __attribute__((address_space(1))) void*)g,
      (__attribute__((address_space(3))) void*)l, 16, 0, 0);
}

// ---------------- fused cast f32 -> f16 for all 7 tensors ----------------
__device__ __forceinline__ void cast8(const float* s, _Float16* d, int i) {
  float4 a = *(const float4*)(s + i);
  float4 b = *(const float4*)(s + i + 4);
  half8 o;
  o[0] = (_Float16)a.x; o[1] = (_Float16)a.y; o[2] = (_Float16)a.z; o[3] = (_Float16)a.w;
  o[4] = (_Float16)b.x; o[5] = (_Float16)b.y; o[6] = (_Float16)b.z; o[7] = (_Float16)b.w;
  *(half8*)(d + i) = o;
}

__global__ void cast_all_kernel(const float* s0, const float* s1, const float* s2,
                                const float* s3, const float* s4, const float* s5,
                                const float* s6, _Float16* d0, _Float16* d1,
                                _Float16* d2, _Float16* d3, _Float16* d4,
                                _Float16* d5, _Float16* d6) {
  int b = blockIdx.x;
  const float* s;
  _Float16* d;
  int off;
  if (b < 2048)      { s = s0; d = d0; off = b; }
  else if (b < 2560) { s = s1; d = d1; off = b - 2048; }
  else if (b < 3072) { s = s2; d = d2; off = b - 2560; }
  else if (b < 3584) { s = s3; d = d3; off = b - 3072; }
  else if (b < 4096) { s = s4; d = d4; off = b - 3584; }
  else if (b < 6144) { s = s5; d = d5; off = b - 4096; }
  else               { s = s6; d = d6; off = b - 6144; }
  cast8(s, d, (off * 256 + threadIdx.x) * 8);
}

// ---------------- LayerNorm + AdaLN modulate -> fp16 ----------------
__global__ void ln_mod_kernel(const float* __restrict__ x, const float* __restrict__ cond,
                              const float* __restrict__ ada, _Float16* __restrict__ out,
                              int sidx, int hidx) {
  int row = blockIdx.x;        // 0..4095 (b*1024 + l)
  int b = row >> 10;
  int t = threadIdx.x;         // 256
  const float* xr = x + (size_t)row * 1024;
  float4 v = *(const float4*)(xr + t * 4);
  float s = v.x + v.y + v.z + v.w;
  float s2 = v.x * v.x + v.y * v.y + v.z * v.z + v.w * v.w;
#pragma unroll
  for (int m = 32; m >= 1; m >>= 1) {
    s += __shfl_xor(s, m, 64);
    s2 += __shfl_xor(s2, m, 64);
  }
  __shared__ float red[8];
  int w = t >> 6;
  if ((t & 63) == 0) { red[w * 2] = s; red[w * 2 + 1] = s2; }
  __syncthreads();
  s = red[0] + red[2] + red[4] + red[6];
  s2 = red[1] + red[3] + red[5] + red[7];
  float mu = s * (1.f / 1024.f);
  float var = s2 * (1.f / 1024.f) - mu * mu;
  float rstd = rsqrtf(var + 1e-5f);
  int c = t * 4;
  float4 sc = *(const float4*)(cond + (size_t)b * 6144 + sidx * 1024 + c);
  float4 sh = *(const float4*)(cond + (size_t)b * 6144 + hidx * 1024 + c);
  float4 sa = *(const float4*)(ada + sidx * 1024 + c);
  float4 ha = *(const float4*)(ada + hidx * 1024 + c);
  half4v o;
  o[0] = (_Float16)((v.x - mu) * rstd * (sc.x + sa.x + 1.f) + sh.x + ha.x);
  o[1] = (_Float16)((v.y - mu) * rstd * (sc.y + sa.y + 1.f) + sh.y + ha.y);
  o[2] = (_Float16)((v.z - mu) * rstd * (sc.z + sa.z + 1.f) + sh.z + ha.z);
  o[3] = (_Float16)((v.w - mu) * rstd * (sc.w + sa.w + 1.f) + sh.w + ha.w);
  *(half4v*)(out + (size_t)row * 1024 + c) = o;
}

// ---------------- fused QKV GEMM: z=0 Q(A=modx), z=1 K(A=ctx), z=2 V->V^T ----------------
__global__ __launch_bounds__(256) void gemm_qkv(
    const _Float16* __restrict__ modx, const _Float16* __restrict__ ctx16,
    const _Float16* __restrict__ wq, const _Float16* __restrict__ wk,
    const _Float16* __restrict__ wv, _Float16* __restrict__ q16,
    _Float16* __restrict__ k16, _Float16* __restrict__ vt16) {
  int z = blockIdx.z;
  const _Float16* A = (z == 0) ? modx : ctx16;
  const _Float16* W = (z == 0) ? wq : ((z == 1) ? wk : wv);
  const int K = 1024;
  __shared__ __align__(16) _Float16 lA[128 * 32];
  __shared__ __align__(16) _Float16 lB[128 * 32];
  int t = threadIdx.x;
  int lane = t & 63;
  int w = t >> 6;
  int wr = w >> 1, wc = w & 1;
  int l16 = lane & 15, lg = lane >> 4;
  int bm = blockIdx.y * 128, bn = blockIdx.x * 128;
  f32x4 acc[4][4] = {};
  int e0 = t * 8;
  int e1 = 2048 + t * 8;
  int r0 = e0 >> 5, c0 = e0 & 31;
  int r1 = e1 >> 5, c1 = e1 & 31;
  const _Float16* Ab = A + (size_t)bm * K;
  const _Float16* Wb = W + (size_t)bn * K;
  for (int kt = 0; kt < K; kt += 32) {
    gl2lds16(Ab + (size_t)r0 * K + kt + c0, &lA[e0]);
    gl2lds16(Ab + (size_t)r1 * K + kt + c1, &lA[e1]);
    gl2lds16(Wb + (size_t)r0 * K + kt + c0, &lB[e0]);
    gl2lds16(Wb + (size_t)r1 * K + kt + c1, &lB[e1]);
    __syncthreads();
    half8 af[4], bf[4];
#pragma unroll
    for (int m = 0; m < 4; ++m)
      af[m] = *(const half8*)&lA[(wr * 64 + m * 16 + l16) * 32 + lg * 8];
#pragma unroll
    for (int n = 0; n < 4; ++n)
      bf[n] = *(const half8*)&lB[(wc * 64 + n * 16 + l16) * 32 + lg * 8];
#pragma unroll
    for (int m = 0; m < 4; ++m)
#pragma unroll
      for (int n = 0; n < 4; ++n)
        acc[m][n] = MFMA16(af[m], bf[n], acc[m][n]);
    __syncthreads();
  }
#pragma unroll
  for (int m = 0; m < 4; ++m) {
#pragma unroll
    for (int n = 0; n < 4; ++n) {
      int gc = bn + wc * 64 + n * 16 + l16;   // channel = h*64+hd
      int gr0 = bm + wr * 64 + m * 16 + lg * 4;  // row = b*1024+l
      int h = gc >> 6, hd = gc & 63;
      if (z < 2) {
        _Float16* dst = (z == 0) ? q16 : k16;
#pragma unroll
        for (int r = 0; r < 4; ++r) {
          int gr = gr0 + r;
          int b = gr >> 10, l = gr & 1023;
          dst[(((size_t)(b * 16 + h)) * 1024 + l) * 64 + hd] = (_Float16)acc[m][n][r];
        }
      } else {
        int b = gr0 >> 10, l = gr0 & 1023;
        half4v hv;
#pragma unroll
        for (int r = 0; r < 4; ++r) hv[r] = (_Float16)acc[m][n][r];
        *(half4v*)&vt16[(((size_t)(b * 16 + h)) * 64 + hd) * 1024 + l] = hv;
      }
    }
  }
}

// ---------------- GEMM: C = A[M,K] * W[N,K]^T, fp16 in, fp32 acc ----------------
// EPI 1: out fp32 = res + (acc + bias)*gamma   EPI 2: out fp16 = gelu(acc+bias)
template <int EPI>
__global__ __launch_bounds__(256) void gemm_f16(
    const _Float16* __restrict__ A, const _Float16* __restrict__ W,
    int M, int N, int K, void* __restrict__ outp,
    const float* __restrict__ bias, const float* __restrict__ res,
    const float* __restrict__ cond, const float* __restrict__ ada, int gidx) {
  __shared__ __align__(16) _Float16 lA[128 * 32];
  __shared__ __align__(16) _Float16 lB[128 * 32];
  int t = threadIdx.x;
  int lane = t & 63;
  int w = t >> 6;
  int wr = w >> 1, wc = w & 1;
  int l16 = lane & 15, lg = lane >> 4;
  int bm = blockIdx.y * 128, bn = blockIdx.x * 128;
  f32x4 acc[4][4] = {};
  int e0 = t * 8;
  int e1 = 2048 + t * 8;
  int r0 = e0 >> 5, c0 = e0 & 31;
  int r1 = e1 >> 5, c1 = e1 & 31;
  const _Float16* Ab = A + (size_t)bm * K;
  const _Float16* Wb = W + (size_t)bn * K;
  for (int kt = 0; kt < K; kt += 32) {
    gl2lds16(Ab + (size_t)r0 * K + kt + c0, &lA[e0]);
    gl2lds16(Ab + (size_t)r1 * K + kt + c1, &lA[e1]);
    gl2lds16(Wb + (size_t)r0 * K + kt + c0, &lB[e0]);
    gl2lds16(Wb + (size_t)r1 * K + kt + c1, &lB[e1]);
    __syncthreads();
    half8 af[4], bf[4];
#pragma unroll
    for (int m = 0; m < 4; ++m)
      af[m] = *(const half8*)&lA[(wr * 64 + m * 16 + l16) * 32 + lg * 8];
#pragma unroll
    for (int n = 0; n < 4; ++n)
      bf[n] = *(const half8*)&lB[(wc * 64 + n * 16 + l16) * 32 + lg * 8];
#pragma unroll
    for (int m = 0; m < 4; ++m)
#pragma unroll
      for (int n = 0; n < 4; ++n)
        acc[m][n] = MFMA16(af[m], bf[n], acc[m][n]);
    __syncthreads();
  }
#pragma unroll
  for (int m = 0; m < 4; ++m) {
#pragma unroll
    for (int n = 0; n < 4; ++n) {
      int gc = bn + wc * 64 + n * 16 + l16;
      int gr0 = bm + wr * 64 + m * 16 + lg * 4;
#pragma unroll
      for (int r = 0; r < 4; ++r) {
        int gr = gr0 + r;
        float v = acc[m][n][r];
        if constexpr (EPI == 1) {
          float g = ada[gidx * 1024 + gc] + cond[(size_t)(gr >> 10) * 6144 + gidx * 1024 + gc];
          ((float*)outp)[(size_t)gr * 1024 + gc] =
              res[(size_t)gr * 1024 + gc] + (v + bias[gc]) * g;
        } else {
          float xx = v + bias[gc];
          float u = 0.7978845608028654f * (xx + 0.044715f * xx * xx * xx);
          float e = __expf(2.f * u);
          float th = (e - 1.f) / (e + 1.f);
          ((_Float16*)outp)[(size_t)gr * 4096 + gc] = (_Float16)(0.5f * xx * (1.f + th));
        }
      }
    }
  }
}

// ---------------- fused flash attention v3: bias staged in LDS ----------------
// grid 4096 (XCD-chunked: bh-major per XCD), 256 thr = 4 waves.
// Block = 16 q-rows; waves split the 1024-key range into 4 quarters (256 keys,
// 4 tiles of 64); partial (m,l,o) merged via LDS at the end. Bias slice
// (16 rows x 4KB) is streamed contiguously into LDS once via global_load_lds
// with pre-swizzled source (XOR on 16B slots within each 128B window).
__global__ __launch_bounds__(256, 2) void attn_kernel(
    const _Float16* __restrict__ q16, const _Float16* __restrict__ k16,
    const _Float16* __restrict__ vt16, const float* __restrict__ bias,
    _Float16* __restrict__ o16) {
  int wg = blockIdx.x;
  int sid = (wg & 7) * 512 + (wg >> 3);  // XCD-chunked bijective swizzle (4096%8==0)
  int bh = sid >> 6, qb = sid & 63;
  int t = threadIdx.x, w = t >> 6, lane = t & 63;
  int l16 = lane & 15, lg = lane >> 4;
  int qRow = qb * 16;

  __shared__ __align__(16) char smem[65536 + 8192 + 512];
  float* biasL = (float*)smem;                       // [16 rows][1024] f32, slot-swizzled
  _Float16* pbuf = (_Float16*)(smem + 65536);        // [4][16][64] halves, XOR-swizzled
  float* sm = (float*)(smem + 65536 + 8192);         // [4][16] running max
  float* sl = sm + 64;                               // [4][16] running sum
  float* soL = (float*)smem;                         // alias of biasL: [4][16][68] f32

  // ---- stage bias into LDS: contiguous global stream, source pre-swizzled ----
  const char* bsrc = (const char*)(bias + (size_t)bh * 1048576 + (size_t)qRow * 1024);
#pragma unroll
  for (int i = 0; i < 16; ++i) {
    int c = w * 16 + i;                 // 1KB chunk id (64 chunks total)
    int S = c * 64 + lane;              // 16B slot index 0..4095
    int r = S >> 8, s = S & 255;        // row, slot-in-row
    int ss = s ^ (r & 7);               // involution: LDS slot s holds global slot ss
    gl2lds16(bsrc + (size_t)r * 4096 + (ss << 4), (char*)smem + c * 1024);
  }

  const size_t bhoff = (size_t)bh * 65536;
  half8 aq[2];
#pragma unroll
  for (int ks = 0; ks < 2; ++ks)
    aq[ks] = *(const half8*)(q16 + bhoff + (size_t)(qRow + l16) * 64 + ks * 32 + lg * 8);
  const _Float16* kb = k16 + bhoff;
  const _Float16* vb = vt16 + bhoff;

  f32x4 oacc[4] = {};
  float mrun = -1e30f, lrun = 0.f;   // per-lane stats for query l16 (replicated over lg)
  __syncthreads();  // bias LDS ready

  int ktw = w * 256;  // this wave's kv quarter
  for (int it = 0; it < 4; ++it) {
    int kt = ktw + it * 64;
    // swapped QK^T: s[kk] holds keys kt+kk*16+lg*4+r for query l16
    f32x4 s[4] = {};
#pragma unroll
    for (int ks = 0; ks < 2; ++ks) {
#pragma unroll
      for (int kk = 0; kk < 4; ++kk) {
        half8 kf = *(const half8*)(kb + (size_t)(kt + kk * 16 + l16) * 64 + ks * 32 + lg * 8);
        s[kk] = MFMA16(kf, aq[ks], s[kk]);
      }
    }
    float p[4][4];
    float tm = -1e30f;
#pragma unroll
    for (int kk = 0; kk < 4; ++kk) {
      int slot = (kt >> 2) + 4 * kk + lg;
      f32x4 bv = *(const f32x4*)(biasL + l16 * 1024 + ((slot ^ (l16 & 7)) << 2));
#pragma unroll
      for (int r = 0; r < 4; ++r) {
        p[kk][r] = s[kk][r] * 0.03125f + bv[r];
        tm = fmaxf(tm, p[kk][r]);
      }
    }
    tm = fmaxf(tm, __shfl_xor(tm, 16, 64));
    tm = fmaxf(tm, __shfl_xor(tm, 32, 64));
    int noskip = !__all(tm <= mrun);  // exact defer-max
    float mnew = noskip ? fmaxf(mrun, tm) : mrun;
    float ts = 0.f;
#pragma unroll
    for (int kk = 0; kk < 4; ++kk)
#pragma unroll
      for (int r = 0; r < 4; ++r) {
        p[kk][r] = exp2f((p[kk][r] - mnew) * 1.442695041f);
        ts += p[kk][r];
      }
    ts += __shfl_xor(ts, 16, 64);
    ts += __shfl_xor(ts, 32, 64);
    if (noskip) {
      float scl = exp2f((mrun - mnew) * 1.442695041f);
      lrun = lrun * scl + ts;
      mrun = mnew;
      float sclr[4];
#pragma unroll
      for (int r = 0; r < 4; ++r) sclr[r] = __shfl(scl, lg * 4 + r, 16);
#pragma unroll
      for (int n = 0; n < 4; ++n)
#pragma unroll
        for (int r = 0; r < 4; ++r) oacc[n][r] *= sclr[r];
    } else {
      lrun += ts;
    }
    // P -> pbuf (row l16 = query, 128B rows, 16B-slot XOR swizzle)
    char* pb = (char*)pbuf + w * 2048 + l16 * 128;
#pragma unroll
    for (int kk = 0; kk < 4; ++kk) {
      half4v ph;
#pragma unroll
      for (int r = 0; r < 4; ++r) ph[r] = (_Float16)p[kk][r];
      int slot = 2 * kk + (lg >> 1);
      *(half4v*)(pb + ((slot ^ (l16 & 7)) << 4) + (lg & 1) * 8) = ph;
    }
    // PV
#pragma unroll
    for (int ks = 0; ks < 2; ++ks) {
      half8 ap = *(const half8*)(pb + (((4 * ks + lg) ^ (l16 & 7)) << 4));
#pragma unroll
      for (int n = 0; n < 4; ++n) {
        half8 bv = *(const half8*)(vb + (size_t)(n * 16 + l16) * 1024 + kt + ks * 32 + lg * 8);
        oacc[n] = MFMA16(ap, bv, oacc[n]);
      }
    }
  }

  // ---- merge the 4 kv-partials (aliases bias region; barrier first) ----
  __syncthreads();
  if (lg == 0) { sm[w * 16 + l16] = mrun; sl[w * 16 + l16] = lrun; }
#pragma unroll
  for (int n = 0; n < 4; ++n)
#pragma unroll
    for (int r = 0; r < 4; ++r)
      soL[(size_t)(w * 16 + lg * 4 + r) * 68 + n * 16 + l16] = oacc[n][r];
  __syncthreads();

  int q = t >> 4, hq = t & 15;
  float m0 = sm[q], m1 = sm[16 + q], m2 = sm[32 + q], m3 = sm[48 + q];
  float M = fmaxf(fmaxf(m0, m1), fmaxf(m2, m3));
  float e0 = exp2f((m0 - M) * 1.442695041f);
  float e1 = exp2f((m1 - M) * 1.442695041f);
  float e2 = exp2f((m2 - M) * 1.442695041f);
  float e3 = exp2f((m3 - M) * 1.442695041f);
  float rd = 1.f / (e0 * sl[q] + e1 * sl[16 + q] + e2 * sl[32 + q] + e3 * sl[48 + q]);
  int b = bh >> 4, h = bh & 15;
  half4v ov;
#pragma unroll
  for (int j = 0; j < 4; ++j) {
    int hd = hq * 4 + j;
    float num = e0 * soL[(size_t)q * 68 + hd] + e1 * soL[(size_t)(16 + q) * 68 + hd] +
                e2 * soL[(size_t)(32 + q) * 68 + hd] + e3 * soL[(size_t)(48 + q) * 68 + hd];
    ov[j] = (_Float16)(num * rd);
  }
  *(half4v*)&o16[((size_t)b * 1024 + qRow + q) * 1024 + h * 64 + hq * 4] = ov;
}

extern "C" void kernel_launch(void* const* d_in, const int* in_sizes, int n_in,
                              void* d_out, int out_size, void* d_ws, size_t ws_size,
                              hipStream_t stream) {
  const float* x = (const float*)d_in[0];
  const float* ctx = (const float*)d_in[1];
  const float* cond = (const float*)d_in[2];
  const float* bias = (const float*)d_in[3];
  const float* ada = (const float*)d_in[4];
  const float* Wq = (const float*)d_in[5];
  const float* Wk = (const float*)d_in[6];
  const float* Wv = (const float*)d_in[7];
  const float* Wo = (const float*)d_in[8];
  const float* bo = (const float*)d_in[9];
  const float* W1 = (const float*)d_in[10];
  const float* b1 = (const float*)d_in[11];
  const float* W2 = (const float*)d_in[12];
  const float* b2 = (const float*)d_in[13];

  char* ws = (char*)d_ws;
  const size_t MB = 1u << 20;
  _Float16* wq16 = (_Float16*)(ws + 0 * MB);
  _Float16* wk16 = (_Float16*)(ws + 2 * MB);
  _Float16* wv16 = (_Float16*)(ws + 4 * MB);
  _Float16* wo16 = (_Float16*)(ws + 6 * MB);
  _Float16* w116 = (_Float16*)(ws + 8 * MB);
  _Float16* w216 = (_Float16*)(ws + 16 * MB);
  _Float16* modx = (_Float16*)(ws + 24 * MB);  // reused for mod_f
  _Float16* ctx16 = (_Float16*)(ws + 32 * MB);
  _Float16* q16 = (_Float16*)(ws + 40 * MB);
  _Float16* k16 = (_Float16*)(ws + 48 * MB);
  _Float16* vt16 = (_Float16*)(ws + 64 * MB);
  _Float16* h16 = (_Float16*)(ws + 40 * MB);  // reuses q/k region (dead by then)
  _Float16* o16 = (_Float16*)(ws + 72 * MB);
  float* x1 = (float*)(ws + 80 * MB);

  cast_all_kernel<<<8192, 256, 0, stream>>>(ctx, Wq, Wk, Wv, Wo, W1, W2,
                                            ctx16, wq16, wk16, wv16, wo16, w116, w216);

  ln_mod_kernel<<<4096, 256, 0, stream>>>(x, cond, ada, modx, 2, 4);

  gemm_qkv<<<dim3(8, 32, 3), 256, 0, stream>>>(modx, ctx16, wq16, wk16, wv16,
                                               q16, k16, vt16);

  attn_kernel<<<4096, 256, 0, stream>>>(q16, k16, vt16, bias, o16);

  dim3 gN1024(8, 32);
  gemm_f16<1><<<gN1024, 256, 0, stream>>>(o16, wo16, 4096, 1024, 1024, x1,
                                          bo, x, cond, ada, 0);

  ln_mod_kernel<<<4096, 256, 0, stream>>>(x1, cond, ada, modx, 3, 5);

  gemm_f16<2><<<dim3(32, 32), 256, 0, stream>>>(modx, w116, 4096, 4096, 1024, h16,
                                                b1, nullptr, nullptr, nullptr, 0);

  gemm_f16<1><<<gN1024, 256, 0, stream>>>(h16, w216, 4096, 1024, 4096, d_out,
                                          b2, x1, cond, ada, 1);
}